// Round 6
// baseline (557.945 us; speedup 1.0000x reference)
//
#include <hip/hip_runtime.h>
#include <hip/hip_bf16.h>
#include <math.h>

#define N_NODES 50000
#define N_EDGES 1600000
#define DIM 128
#define EPS 1e-5f
#define SLOPE 0.2f

#define NBUCK 256
#define NPB 196        // nodes per bucket (ceil 50000/256)
#define EPB 4096       // edges per partB block
#define NBLK_B ((N_EDGES + EPB - 1) / EPB)

typedef __attribute__((ext_vector_type(8))) short bf16x8;
typedef __attribute__((ext_vector_type(4))) float f32x4;

__device__ __forceinline__ float lrelu(float x) { return x > 0.f ? x : SLOPE * x; }

__device__ __forceinline__ unsigned short f2bf(float f) {
    unsigned u = __float_as_uint(f);
    unsigned r = (u + 0x7fffu + ((u >> 16) & 1u)) >> 16;
    return (unsigned short)r;
}

__device__ __forceinline__ float2 ldh2(const unsigned short* p) {
    unsigned u = *(const unsigned*)p;
    float2 r;
    r.x = __uint_as_float(u << 16);
    r.y = __uint_as_float(u & 0xffff0000u);
    return r;
}

__device__ __forceinline__ float2 bf2f2(unsigned u) {
    float2 r;
    r.x = __uint_as_float(u << 16);
    r.y = __uint_as_float(u & 0xffff0000u);
    return r;
}

// ---------------- build step 1: coarse bucket histogram (bucket = dst / 196)
__global__ void k_hist(const int* __restrict__ dst, int* __restrict__ bcnt) {
    __shared__ int h[NBUCK];
    int tid = threadIdx.x;
    h[tid] = 0;
    __syncthreads();
    int nq = N_EDGES / 4;
    for (int q = blockIdx.x * 256 + tid; q < nq; q += gridDim.x * 256) {
        int4 d = ((const int4*)dst)[q];
        atomicAdd(&h[d.x / NPB], 1);
        atomicAdd(&h[d.y / NPB], 1);
        atomicAdd(&h[d.z / NPB], 1);
        atomicAdd(&h[d.w / NPB], 1);
    }
    __syncthreads();
    if (h[tid]) atomicAdd(&bcnt[tid], h[tid]);
}

// ---------------- build step 2: scan bucket counts -> bases + gtail copy
__global__ void k_bscan(const int* __restrict__ bcnt, int* __restrict__ bbase,
                        int* __restrict__ gtail) {
    __shared__ int s[NBUCK];
    int t = threadIdx.x;
    int v = bcnt[t];
    s[t] = v;
    __syncthreads();
    for (int off = 1; off < NBUCK; off <<= 1) {
        int x = s[t];
        int y = (t >= off) ? s[t - off] : 0;
        __syncthreads();
        s[t] = x + y;
        __syncthreads();
    }
    bbase[t] = s[t] - v;
    gtail[t] = s[t] - v;
    if (t == NBUCK - 1) bbase[NBUCK] = s[NBUCK - 1];
}

// ---------------- build step 3: partition edges into bucket-segmented staged[]
__global__ __launch_bounds__(256) void k_partB(const int* __restrict__ src,
                                               const int* __restrict__ dst,
                                               int* __restrict__ gtail,
                                               uint2* __restrict__ staged) {
    __shared__ int cnt[NBUCK];
    __shared__ int bas[NBUCK];
    int tid = threadIdx.x;
    cnt[tid] = 0;
    __syncthreads();
    int e0 = blockIdx.x * EPB;
#pragma unroll 4
    for (int i = 0; i < EPB / 256; ++i) {
        int e = e0 + i * 256 + tid;
        if (e < N_EDGES) atomicAdd(&cnt[dst[e] / NPB], 1);
    }
    __syncthreads();
    {
        int c = cnt[tid];
        bas[tid] = c ? atomicAdd(&gtail[tid], c) : 0;
    }
    __syncthreads();
    cnt[tid] = 0;
    __syncthreads();
#pragma unroll 4
    for (int i = 0; i < EPB / 256; ++i) {
        int e = e0 + i * 256 + tid;
        if (e < N_EDGES) {
            int d = dst[e], s = src[e];
            int b = d / NPB;
            int off = atomicAdd(&cnt[b], 1);
            staged[bas[b] + off] = make_uint2((unsigned)s, (unsigned)d);
        }
    }
}

// ---------------- build step 4: per-bucket grouping; writes row_ptr AND col_src
__global__ __launch_bounds__(256) void k_partC(const uint2* __restrict__ staged,
                                               const int* __restrict__ bbase,
                                               int* __restrict__ row_ptr,
                                               int* __restrict__ col_src) {
    __shared__ int cnt[NBUCK];
    __shared__ int loc[NBUCK];
    __shared__ int s[NBUCK];
    int b = blockIdx.x, tid = threadIdx.x;
    int d0 = b * NPB;
    int d1 = d0 + NPB;
    if (d1 > N_NODES) d1 = N_NODES;
    int nn = d1 - d0;
    int s0 = bbase[b], s1 = bbase[b + 1];

    cnt[tid] = 0;
    __syncthreads();
    for (int e = s0 + tid; e < s1; e += 256) {
        int d = (int)staged[e].y;
        atomicAdd(&cnt[d - d0], 1);
    }
    __syncthreads();
    {
        int v = cnt[tid];
        s[tid] = v;
        __syncthreads();
        for (int off = 1; off < NBUCK; off <<= 1) {
            int x = s[tid];
            int y = (tid >= off) ? s[tid - off] : 0;
            __syncthreads();
            s[tid] = x + y;
            __syncthreads();
        }
        loc[tid] = s[tid] - v;
    }
    if (tid < nn) row_ptr[d0 + tid] = s0 + loc[tid];
    if (b == 0 && tid == 0) row_ptr[N_NODES] = N_EDGES;
    cnt[tid] = 0;
    __syncthreads();
    for (int e = s0 + tid; e < s1; e += 256) {
        uint2 sd = staged[e];
        int d = (int)sd.y;
        int pos = s0 + loc[d - d0] + atomicAdd(&cnt[d - d0], 1);
        col_src[pos] = (int)sd.x;
    }
}

// ---------------- prep: W[l] (fp32 [k][c]) -> Wt (bf16 [c][k]), all 3 layers
__global__ void k_prepW(const float* __restrict__ W, unsigned short* __restrict__ Wt) {
    int idx = blockIdx.x * 256 + threadIdx.x;
    int l = idx >> 14;
    int k = (idx >> 7) & 127;
    int c = idx & 127;
    Wt[l * 16384 + c * 128 + k] = f2bf(W[l * 16384 + k * 128 + c]);
}

// ---------------- MFMA GEMM with fused BN+ReLU input and fused alpha epilogue
__global__ __launch_bounds__(256) void k_gemm_mfma(const float* __restrict__ Z,
                                                   const unsigned short* __restrict__ Wt,
                                                   unsigned short* __restrict__ Hb,
                                                   const float* __restrict__ mu,
                                                   const float* __restrict__ rs,
                                                   const float* __restrict__ a_src,
                                                   const float* __restrict__ a_dst,
                                                   float* __restrict__ as_,
                                                   float* __restrict__ ad_) {
    __shared__ unsigned short Bs[128 * 128];
    int tid = threadIdx.x;
    int lane = tid & 63, wave = tid >> 6;

    {   // stage Wt[c][k] -> Bs swizzled: byte = (c*256 + k*2) ^ ((c&7)<<4)
        int c = tid >> 1, kh = tid & 1;
        const unsigned short* gsrc = &Wt[c * 128 + kh * 64];
#pragma unroll
        for (int ch = 0; ch < 8; ++ch) {
            int byte_off = (c * 256 + kh * 128 + ch * 16) ^ ((c & 7) << 4);
            *(int4*)((char*)Bs + byte_off) = *(const int4*)(gsrc + ch * 8);
        }
    }

    int r0 = blockIdx.x * 128 + wave * 32;
    bf16x8 afr[2][4];
#pragma unroll
    for (int rt = 0; rt < 2; ++rt) {
        int row = r0 + rt * 16 + (lane & 15);
        const float* zrow = &Z[(size_t)row * 128];
#pragma unroll
        for (int ks = 0; ks < 4; ++ks) {
            int k = ks * 32 + (lane >> 4) * 8;
            bf16x8 fr = (bf16x8){0, 0, 0, 0, 0, 0, 0, 0};
            if (row < N_NODES) {
                float4 a = *(const float4*)&zrow[k];
                float4 b = *(const float4*)&zrow[k + 4];
                if (mu) {
                    float4 m0 = *(const float4*)&mu[k];
                    float4 m1 = *(const float4*)&mu[k + 4];
                    float4 r0v = *(const float4*)&rs[k];
                    float4 r1v = *(const float4*)&rs[k + 4];
                    a.x = fmaxf((a.x - m0.x) * r0v.x, 0.f);
                    a.y = fmaxf((a.y - m0.y) * r0v.y, 0.f);
                    a.z = fmaxf((a.z - m0.z) * r0v.z, 0.f);
                    a.w = fmaxf((a.w - m0.w) * r0v.w, 0.f);
                    b.x = fmaxf((b.x - m1.x) * r1v.x, 0.f);
                    b.y = fmaxf((b.y - m1.y) * r1v.y, 0.f);
                    b.z = fmaxf((b.z - m1.z) * r1v.z, 0.f);
                    b.w = fmaxf((b.w - m1.w) * r1v.w, 0.f);
                }
                fr[0] = (short)f2bf(a.x); fr[1] = (short)f2bf(a.y);
                fr[2] = (short)f2bf(a.z); fr[3] = (short)f2bf(a.w);
                fr[4] = (short)f2bf(b.x); fr[5] = (short)f2bf(b.y);
                fr[6] = (short)f2bf(b.z); fr[7] = (short)f2bf(b.w);
            }
            afr[rt][ks] = fr;
        }
    }

    float asv[8], adv[8];
#pragma unroll
    for (int ct = 0; ct < 8; ++ct) {
        int c = ct * 16 + (lane & 15);
        asv[ct] = a_src[c];
        adv[ct] = a_dst[c];
    }
    __syncthreads();

    f32x4 acc[2][8];
#pragma unroll
    for (int rt = 0; rt < 2; ++rt)
#pragma unroll
        for (int ct = 0; ct < 8; ++ct) acc[rt][ct] = (f32x4){0.f, 0.f, 0.f, 0.f};

#pragma unroll
    for (int ct = 0; ct < 8; ++ct) {
        int c = ct * 16 + (lane & 15);
#pragma unroll
        for (int ks = 0; ks < 4; ++ks) {
            int k = ks * 32 + (lane >> 4) * 8;
            int byte_off = (c * 256 + k * 2) ^ ((c & 7) << 4);
            bf16x8 bfr = *(const bf16x8*)((char*)Bs + byte_off);
            acc[0][ct] = __builtin_amdgcn_mfma_f32_16x16x32_bf16(afr[0][ks], bfr, acc[0][ct], 0, 0, 0);
            acc[1][ct] = __builtin_amdgcn_mfma_f32_16x16x32_bf16(afr[1][ks], bfr, acc[1][ct], 0, 0, 0);
        }
    }

#pragma unroll
    for (int rt = 0; rt < 2; ++rt) {
#pragma unroll
        for (int ct = 0; ct < 8; ++ct) {
            int c = ct * 16 + (lane & 15);
#pragma unroll
            for (int j = 0; j < 4; ++j) {
                int row = r0 + rt * 16 + (lane >> 4) * 4 + j;
                if (row < N_NODES) Hb[(size_t)row * 128 + c] = f2bf(acc[rt][ct][j]);
            }
        }
#pragma unroll
        for (int j = 0; j < 4; ++j) {
            float ps = 0.f, pd = 0.f;
#pragma unroll
            for (int ct = 0; ct < 8; ++ct) {
                float v = acc[rt][ct][j];
                ps += v * asv[ct];
                pd += v * adv[ct];
            }
#pragma unroll
            for (int off = 8; off; off >>= 1) {
                ps += __shfl_xor(ps, off);
                pd += __shfl_xor(pd, off);
            }
            int row = r0 + rt * 16 + (lane >> 4) * 4 + j;
            if ((lane & 15) == 0 && row < N_NODES) {
                as_[row] = ps;
                ad_[row] = pd;
            }
        }
    }
}

// ---------------- segment softmax + weighted aggregation (one wave per dst node)
// Gather: 4 edges per iteration, 16 lanes x 16B per edge.
__global__ void k_aggregate(const int* __restrict__ row_ptr, const int* __restrict__ col_src,
                            const unsigned short* __restrict__ Hb,
                            const float* __restrict__ as_, const float* __restrict__ ad_,
                            const float* __restrict__ bias, float* __restrict__ Zout,
                            float* __restrict__ ebuf) {
    int node = blockIdx.x * 4 + (threadIdx.x >> 6);
    int lane = threadIdx.x & 63;
    if (node >= N_NODES) return;
    int g = lane >> 4;       // edge group 0..3
    int fl = lane & 15;      // feature lanes: features fl*8 .. fl*8+7

    int start = row_ptr[node], end = row_ptr[node + 1];
    int deg = end - start;
    float ad_i = ad_[node];
    float eself = lrelu(as_[node] + ad_i);
    float m = eself;
    float acc[8];
#pragma unroll
    for (int f = 0; f < 8; ++f) acc[f] = 0.f;
    float wself;

    if (deg <= 128) {
        int s0 = 0, s1 = 0;
        float e0 = -INFINITY, e1 = -INFINITY;
        if (start + lane < end) {
            s0 = col_src[start + lane];
            e0 = lrelu(as_[s0] + ad_i);
            m = fmaxf(m, e0);
        }
        if (start + 64 + lane < end) {
            s1 = col_src[start + 64 + lane];
            e1 = lrelu(as_[s1] + ad_i);
            m = fmaxf(m, e1);
        }
#pragma unroll
        for (int off = 32; off; off >>= 1) m = fmaxf(m, __shfl_xor(m, off));
        float w0 = __expf(e0 - m);   // 0 for invalid lanes
        float w1 = __expf(e1 - m);
        float p = w0 + w1;
#pragma unroll
        for (int off = 32; off; off >>= 1) p += __shfl_xor(p, off);
        float pself = __expf(eself - m);
        float inv_s = 1.f / (p + pself);
        w0 *= inv_s;
        w1 *= inv_s;
        wself = pself * inv_s;

        int jmax = deg < 64 ? deg : 64;
        for (int j = 0; j < jmax; j += 4) {
            int idx = j + g;                       // <= 63 always
            float w = __shfl(w0, idx);             // 0 beyond deg
            int sv = __shfl(s0, idx);
            uint4 hv = *(const uint4*)&Hb[(size_t)sv * 128 + fl * 8];
            float2 a0 = bf2f2(hv.x), a1 = bf2f2(hv.y), a2 = bf2f2(hv.z), a3 = bf2f2(hv.w);
            acc[0] += w * a0.x; acc[1] += w * a0.y;
            acc[2] += w * a1.x; acc[3] += w * a1.y;
            acc[4] += w * a2.x; acc[5] += w * a2.y;
            acc[6] += w * a3.x; acc[7] += w * a3.y;
        }
        for (int j = 64; j < deg; j += 4) {
            int idx = j - 64 + g;
            float w = __shfl(w1, idx);
            int sv = __shfl(s1, idx);
            uint4 hv = *(const uint4*)&Hb[(size_t)sv * 128 + fl * 8];
            float2 a0 = bf2f2(hv.x), a1 = bf2f2(hv.y), a2 = bf2f2(hv.z), a3 = bf2f2(hv.w);
            acc[0] += w * a0.x; acc[1] += w * a0.y;
            acc[2] += w * a1.x; acc[3] += w * a1.y;
            acc[4] += w * a2.x; acc[5] += w * a2.y;
            acc[6] += w * a3.x; acc[7] += w * a3.y;
        }
    } else {
        for (int j = start + lane; j < end; j += 64) {
            int sj = col_src[j];
            float e = lrelu(as_[sj] + ad_i);
            ebuf[j] = e;
            m = fmaxf(m, e);
        }
#pragma unroll
        for (int off = 32; off; off >>= 1) m = fmaxf(m, __shfl_xor(m, off));
        float p = 0.f;
        for (int j = start + lane; j < end; j += 64) p += __expf(ebuf[j] - m);
#pragma unroll
        for (int off = 32; off; off >>= 1) p += __shfl_xor(p, off);
        float pself = __expf(eself - m);
        float inv_s = 1.f / (p + pself);
        wself = pself * inv_s;
        for (int j = start; j < end; j += 4) {
            int e = j + g;
            float w = 0.f;
            int sv = 0;
            if (e < end) {
                w = __expf(ebuf[e] - m) * inv_s;
                sv = col_src[e];
            }
            uint4 hv = *(const uint4*)&Hb[(size_t)sv * 128 + fl * 8];
            float2 a0 = bf2f2(hv.x), a1 = bf2f2(hv.y), a2 = bf2f2(hv.z), a3 = bf2f2(hv.w);
            acc[0] += w * a0.x; acc[1] += w * a0.y;
            acc[2] += w * a1.x; acc[3] += w * a1.y;
            acc[4] += w * a2.x; acc[5] += w * a2.y;
            acc[6] += w * a3.x; acc[7] += w * a3.y;
        }
    }

    // combine the 4 edge-group partials
#pragma unroll
    for (int f = 0; f < 8; ++f) {
        acc[f] += __shfl_xor(acc[f], 16);
        acc[f] += __shfl_xor(acc[f], 32);
    }

    if (g == 0) {
        uint4 hv = *(const uint4*)&Hb[(size_t)node * 128 + fl * 8];
        float2 a0 = bf2f2(hv.x), a1 = bf2f2(hv.y), a2 = bf2f2(hv.z), a3 = bf2f2(hv.w);
        float4 b0 = *(const float4*)&bias[fl * 8];
        float4 b1 = *(const float4*)&bias[fl * 8 + 4];
        float4 o0, o1;
        o0.x = acc[0] + wself * a0.x + b0.x;
        o0.y = acc[1] + wself * a0.y + b0.y;
        o0.z = acc[2] + wself * a1.x + b0.z;
        o0.w = acc[3] + wself * a1.y + b0.w;
        o1.x = acc[4] + wself * a2.x + b1.x;
        o1.y = acc[5] + wself * a2.y + b1.y;
        o1.z = acc[6] + wself * a3.x + b1.z;
        o1.w = acc[7] + wself * a3.y + b1.w;
        *(float4*)&Zout[(size_t)node * 128 + fl * 8] = o0;
        *(float4*)&Zout[(size_t)node * 128 + fl * 8 + 4] = o1;
    }
}

// ---------------- BatchNorm stats (training, biased var)
__global__ void k_bnstats(const float* __restrict__ Z, float* __restrict__ part) {
    int c = threadIdx.x;
    float s = 0.f, sq = 0.f;
    for (int i = blockIdx.x; i < N_NODES; i += gridDim.x) {
        float v = Z[(size_t)i * 128 + c];
        s += v;
        sq += v * v;
    }
    part[blockIdx.x * 256 + c] = s;
    part[blockIdx.x * 256 + 128 + c] = sq;
}

__global__ void k_bnfinal(const float* __restrict__ part, float* __restrict__ mu,
                          float* __restrict__ rs) {
    __shared__ float ss[4][128];
    __shared__ float sqq[4][128];
    int c = threadIdx.x & 127;
    int q = threadIdx.x >> 7;   // 0..3
    float s = 0.f, sq = 0.f;
    for (int b = q; b < 512; b += 4) {
        s += part[b * 256 + c];
        sq += part[b * 256 + 128 + c];
    }
    ss[q][c] = s;
    sqq[q][c] = sq;
    __syncthreads();
    if (q == 0) {
        s = ss[0][c] + ss[1][c] + ss[2][c] + ss[3][c];
        sq = sqq[0][c] + sqq[1][c] + sqq[2][c] + sqq[3][c];
        float m = s / (float)N_NODES;
        float var = sq / (float)N_NODES - m * m;
        mu[c] = m;
        rs[c] = rsqrtf(var + EPS);
    }
}

// final-layer BN+ReLU apply -> fp32 out
__global__ void k_bnapply(const float* __restrict__ Zin, const float* __restrict__ mu,
                          const float* __restrict__ rs, float* __restrict__ Zout) {
    int idx = blockIdx.x * blockDim.x + threadIdx.x;
    if (idx >= N_NODES * 32) return;
    int c4 = idx & 31;
    float4 v = ((const float4*)Zin)[idx];
    float4 m4 = ((const float4*)mu)[c4];
    float4 r4 = ((const float4*)rs)[c4];
    v.x = fmaxf((v.x - m4.x) * r4.x, 0.f);
    v.y = fmaxf((v.y - m4.y) * r4.y, 0.f);
    v.z = fmaxf((v.z - m4.z) * r4.z, 0.f);
    v.w = fmaxf((v.w - m4.w) * r4.w, 0.f);
    ((float4*)Zout)[idx] = v;
}

extern "C" void kernel_launch(void* const* d_in, const int* in_sizes, int n_in,
                              void* d_out, int out_size, void* d_ws, size_t ws_size,
                              hipStream_t stream) {
    const float* x = (const float*)d_in[0];
    const int* ei = (const int*)d_in[1];
    const int* srcp = ei;
    const int* dstp = ei + N_EDGES;
    const float* W = (const float*)d_in[2];
    const float* a_src = (const float*)d_in[3];
    const float* a_dst = (const float*)d_in[4];
    const float* bias = (const float*)d_in[5];
    float* out = (float*)d_out;

    char* ws = (char*)d_ws;
    size_t off = 0;
    auto alloc = [&](size_t bytes) -> void* {
        void* p = ws + off;
        off = (off + bytes + 255) & ~(size_t)255;
        return p;
    };
    int* bcnt     = (int*)alloc(NBUCK * 4);
    int* bbase    = (int*)alloc((NBUCK + 1) * 4);
    int* gtail    = (int*)alloc(NBUCK * 4);
    int* row_ptr  = (int*)alloc((N_NODES + 1) * 4);
    int* col_src  = (int*)alloc(N_EDGES * 4);
    uint2* staged = (uint2*)alloc((size_t)N_EDGES * 8);   // aliased by ebuf later
    unsigned short* hbf = (unsigned short*)alloc((size_t)N_NODES * DIM * 2);
    float* zbuf   = (float*)alloc((size_t)N_NODES * DIM * 4);
    unsigned short* wtb = (unsigned short*)alloc(3 * 16384 * 2);
    float* asb    = (float*)alloc(N_NODES * 4);
    float* adb    = (float*)alloc(N_NODES * 4);
    float* part   = (float*)alloc(512 * 256 * 4);
    float* mu     = (float*)alloc(128 * 4);
    float* rsg    = (float*)alloc(128 * 4);
    if (off > ws_size) return;

    float* ebuf = (float*)staged;   // aggregate-only scratch (after partC done)

    hipMemsetAsync(bcnt, 0, NBUCK * 4, stream);
    k_hist<<<256, 256, 0, stream>>>(dstp, bcnt);
    k_bscan<<<1, NBUCK, 0, stream>>>(bcnt, bbase, gtail);
    k_partB<<<NBLK_B, 256, 0, stream>>>(srcp, dstp, gtail, staged);
    k_partC<<<NBUCK, 256, 0, stream>>>(staged, bbase, row_ptr, col_src);
    k_prepW<<<192, 256, 0, stream>>>(W, wtb);

    const float* zin = x;
    for (int l = 0; l < 3; ++l) {
        k_gemm_mfma<<<(N_NODES + 127) / 128, 256, 0, stream>>>(
            zin, wtb + l * 16384, hbf, (l == 0) ? nullptr : mu, rsg,
            a_src + l * DIM, a_dst + l * DIM, asb, adb);
        k_aggregate<<<(N_NODES + 3) / 4, 256, 0, stream>>>(row_ptr, col_src, hbf, asb, adb,
                                                           bias + l * DIM, zbuf, ebuf);
        k_bnstats<<<512, 128, 0, stream>>>(zbuf, part);
        k_bnfinal<<<1, 512, 0, stream>>>(part, mu, rsg);
        if (l == 2)
            k_bnapply<<<(N_NODES * 32 + 255) / 256, 256, 0, stream>>>(zbuf, mu, rsg, out);
        zin = zbuf;
    }
}

// Round 7
// 551.544 us; speedup vs baseline: 1.0116x; 1.0116x over previous
//
#include <hip/hip_runtime.h>
#include <hip/hip_bf16.h>
#include <math.h>

#define N_NODES 50000
#define N_EDGES 1600000
#define DIM 128
#define EPS 1e-5f
#define SLOPE 0.2f

#define NBUCK 256
#define NPB 196        // nodes per bucket (ceil 50000/256)
#define EPB 4096       // edges per partB block
#define NBLK_B ((N_EDGES + EPB - 1) / EPB)

typedef __attribute__((ext_vector_type(8))) short bf16x8;
typedef __attribute__((ext_vector_type(4))) float f32x4;

__device__ __forceinline__ float lrelu(float x) { return x > 0.f ? x : SLOPE * x; }

__device__ __forceinline__ unsigned short f2bf(float f) {
    unsigned u = __float_as_uint(f);
    unsigned r = (u + 0x7fffu + ((u >> 16) & 1u)) >> 16;
    return (unsigned short)r;
}

__device__ __forceinline__ float2 bf2f2(unsigned u) {
    float2 r;
    r.x = __uint_as_float(u << 16);
    r.y = __uint_as_float(u & 0xffff0000u);
    return r;
}

// ---------------- build step 1: coarse bucket histogram (bucket = dst / 196)
__global__ void k_hist(const int* __restrict__ dst, int* __restrict__ bcnt) {
    __shared__ int h[NBUCK];
    int tid = threadIdx.x;
    h[tid] = 0;
    __syncthreads();
    int nq = N_EDGES / 4;
    for (int q = blockIdx.x * 256 + tid; q < nq; q += gridDim.x * 256) {
        int4 d = ((const int4*)dst)[q];
        atomicAdd(&h[d.x / NPB], 1);
        atomicAdd(&h[d.y / NPB], 1);
        atomicAdd(&h[d.z / NPB], 1);
        atomicAdd(&h[d.w / NPB], 1);
    }
    __syncthreads();
    if (h[tid]) atomicAdd(&bcnt[tid], h[tid]);
}

// ---------------- build step 2: scan bucket counts -> bases + gtail copy
__global__ void k_bscan(const int* __restrict__ bcnt, int* __restrict__ bbase,
                        int* __restrict__ gtail) {
    __shared__ int s[NBUCK];
    int t = threadIdx.x;
    int v = bcnt[t];
    s[t] = v;
    __syncthreads();
    for (int off = 1; off < NBUCK; off <<= 1) {
        int x = s[t];
        int y = (t >= off) ? s[t - off] : 0;
        __syncthreads();
        s[t] = x + y;
        __syncthreads();
    }
    bbase[t] = s[t] - v;
    gtail[t] = s[t] - v;
    if (t == NBUCK - 1) bbase[NBUCK] = s[NBUCK - 1];
}

// ---------------- build step 3: partition edges into bucket-segmented staged[]
__global__ __launch_bounds__(256) void k_partB(const int* __restrict__ src,
                                               const int* __restrict__ dst,
                                               int* __restrict__ gtail,
                                               uint2* __restrict__ staged) {
    __shared__ int cnt[NBUCK];
    __shared__ int bas[NBUCK];
    int tid = threadIdx.x;
    cnt[tid] = 0;
    __syncthreads();
    int e0 = blockIdx.x * EPB;
#pragma unroll 4
    for (int i = 0; i < EPB / 256; ++i) {
        int e = e0 + i * 256 + tid;
        if (e < N_EDGES) atomicAdd(&cnt[dst[e] / NPB], 1);
    }
    __syncthreads();
    {
        int c = cnt[tid];
        bas[tid] = c ? atomicAdd(&gtail[tid], c) : 0;
    }
    __syncthreads();
    cnt[tid] = 0;
    __syncthreads();
#pragma unroll 4
    for (int i = 0; i < EPB / 256; ++i) {
        int e = e0 + i * 256 + tid;
        if (e < N_EDGES) {
            int d = dst[e], s = src[e];
            int b = d / NPB;
            int off = atomicAdd(&cnt[b], 1);
            staged[bas[b] + off] = make_uint2((unsigned)s, (unsigned)d);
        }
    }
}

// ---------------- build step 4: per-bucket grouping; writes row_ptr AND col_src
__global__ __launch_bounds__(256) void k_partC(const uint2* __restrict__ staged,
                                               const int* __restrict__ bbase,
                                               int* __restrict__ row_ptr,
                                               int* __restrict__ col_src) {
    __shared__ int cnt[NBUCK];
    __shared__ int loc[NBUCK];
    __shared__ int s[NBUCK];
    int b = blockIdx.x, tid = threadIdx.x;
    int d0 = b * NPB;
    int d1 = d0 + NPB;
    if (d1 > N_NODES) d1 = N_NODES;
    int nn = d1 - d0;
    int s0 = bbase[b], s1 = bbase[b + 1];

    cnt[tid] = 0;
    __syncthreads();
    for (int e = s0 + tid; e < s1; e += 256) {
        int d = (int)staged[e].y;
        atomicAdd(&cnt[d - d0], 1);
    }
    __syncthreads();
    {
        int v = cnt[tid];
        s[tid] = v;
        __syncthreads();
        for (int off = 1; off < NBUCK; off <<= 1) {
            int x = s[tid];
            int y = (tid >= off) ? s[tid - off] : 0;
            __syncthreads();
            s[tid] = x + y;
            __syncthreads();
        }
        loc[tid] = s[tid] - v;
    }
    if (tid < nn) row_ptr[d0 + tid] = s0 + loc[tid];
    if (b == 0 && tid == 0) row_ptr[N_NODES] = N_EDGES;
    cnt[tid] = 0;
    __syncthreads();
    for (int e = s0 + tid; e < s1; e += 256) {
        uint2 sd = staged[e];
        int d = (int)sd.y;
        int pos = s0 + loc[d - d0] + atomicAdd(&cnt[d - d0], 1);
        col_src[pos] = (int)sd.x;
    }
}

// ---------------- prep: W[l] (fp32 [k][c]) -> Wt (bf16 [c][k]), all 3 layers
__global__ void k_prepW(const float* __restrict__ W, unsigned short* __restrict__ Wt) {
    int idx = blockIdx.x * 256 + threadIdx.x;
    int l = idx >> 14;
    int k = (idx >> 7) & 127;
    int c = idx & 127;
    Wt[l * 16384 + c * 128 + k] = f2bf(W[l * 16384 + k * 128 + c]);
}

// ---------------- MFMA GEMM with fused BN+ReLU input and fused alpha epilogue
__global__ __launch_bounds__(256) void k_gemm_mfma(const float* __restrict__ Z,
                                                   const unsigned short* __restrict__ Wt,
                                                   unsigned short* __restrict__ Hb,
                                                   const float* __restrict__ mu,
                                                   const float* __restrict__ rs,
                                                   const float* __restrict__ a_src,
                                                   const float* __restrict__ a_dst,
                                                   float* __restrict__ as_,
                                                   float* __restrict__ ad_) {
    __shared__ unsigned short Bs[128 * 128];
    int tid = threadIdx.x;
    int lane = tid & 63, wave = tid >> 6;

    {   // stage Wt[c][k] -> Bs swizzled: byte = (c*256 + k*2) ^ ((c&7)<<4)
        int c = tid >> 1, kh = tid & 1;
        const unsigned short* gsrc = &Wt[c * 128 + kh * 64];
#pragma unroll
        for (int ch = 0; ch < 8; ++ch) {
            int byte_off = (c * 256 + kh * 128 + ch * 16) ^ ((c & 7) << 4);
            *(int4*)((char*)Bs + byte_off) = *(const int4*)(gsrc + ch * 8);
        }
    }

    int r0 = blockIdx.x * 128 + wave * 32;
    bf16x8 afr[2][4];
#pragma unroll
    for (int rt = 0; rt < 2; ++rt) {
        int row = r0 + rt * 16 + (lane & 15);
        const float* zrow = &Z[(size_t)row * 128];
#pragma unroll
        for (int ks = 0; ks < 4; ++ks) {
            int k = ks * 32 + (lane >> 4) * 8;
            bf16x8 fr = (bf16x8){0, 0, 0, 0, 0, 0, 0, 0};
            if (row < N_NODES) {
                float4 a = *(const float4*)&zrow[k];
                float4 b = *(const float4*)&zrow[k + 4];
                if (mu) {
                    float4 m0 = *(const float4*)&mu[k];
                    float4 m1 = *(const float4*)&mu[k + 4];
                    float4 r0v = *(const float4*)&rs[k];
                    float4 r1v = *(const float4*)&rs[k + 4];
                    a.x = fmaxf((a.x - m0.x) * r0v.x, 0.f);
                    a.y = fmaxf((a.y - m0.y) * r0v.y, 0.f);
                    a.z = fmaxf((a.z - m0.z) * r0v.z, 0.f);
                    a.w = fmaxf((a.w - m0.w) * r0v.w, 0.f);
                    b.x = fmaxf((b.x - m1.x) * r1v.x, 0.f);
                    b.y = fmaxf((b.y - m1.y) * r1v.y, 0.f);
                    b.z = fmaxf((b.z - m1.z) * r1v.z, 0.f);
                    b.w = fmaxf((b.w - m1.w) * r1v.w, 0.f);
                }
                fr[0] = (short)f2bf(a.x); fr[1] = (short)f2bf(a.y);
                fr[2] = (short)f2bf(a.z); fr[3] = (short)f2bf(a.w);
                fr[4] = (short)f2bf(b.x); fr[5] = (short)f2bf(b.y);
                fr[6] = (short)f2bf(b.z); fr[7] = (short)f2bf(b.w);
            }
            afr[rt][ks] = fr;
        }
    }

    float asv[8], adv[8];
#pragma unroll
    for (int ct = 0; ct < 8; ++ct) {
        int c = ct * 16 + (lane & 15);
        asv[ct] = a_src[c];
        adv[ct] = a_dst[c];
    }
    __syncthreads();

    f32x4 acc[2][8];
#pragma unroll
    for (int rt = 0; rt < 2; ++rt)
#pragma unroll
        for (int ct = 0; ct < 8; ++ct) acc[rt][ct] = (f32x4){0.f, 0.f, 0.f, 0.f};

#pragma unroll
    for (int ct = 0; ct < 8; ++ct) {
        int c = ct * 16 + (lane & 15);
#pragma unroll
        for (int ks = 0; ks < 4; ++ks) {
            int k = ks * 32 + (lane >> 4) * 8;
            int byte_off = (c * 256 + k * 2) ^ ((c & 7) << 4);
            bf16x8 bfr = *(const bf16x8*)((char*)Bs + byte_off);
            acc[0][ct] = __builtin_amdgcn_mfma_f32_16x16x32_bf16(afr[0][ks], bfr, acc[0][ct], 0, 0, 0);
            acc[1][ct] = __builtin_amdgcn_mfma_f32_16x16x32_bf16(afr[1][ks], bfr, acc[1][ct], 0, 0, 0);
        }
    }

#pragma unroll
    for (int rt = 0; rt < 2; ++rt) {
#pragma unroll
        for (int ct = 0; ct < 8; ++ct) {
            int c = ct * 16 + (lane & 15);
#pragma unroll
            for (int j = 0; j < 4; ++j) {
                int row = r0 + rt * 16 + (lane >> 4) * 4 + j;
                if (row < N_NODES) Hb[(size_t)row * 128 + c] = f2bf(acc[rt][ct][j]);
            }
        }
#pragma unroll
        for (int j = 0; j < 4; ++j) {
            float ps = 0.f, pd = 0.f;
#pragma unroll
            for (int ct = 0; ct < 8; ++ct) {
                float v = acc[rt][ct][j];
                ps += v * asv[ct];
                pd += v * adv[ct];
            }
#pragma unroll
            for (int off = 8; off; off >>= 1) {
                ps += __shfl_xor(ps, off);
                pd += __shfl_xor(pd, off);
            }
            int row = r0 + rt * 16 + (lane >> 4) * 4 + j;
            if ((lane & 15) == 0 && row < N_NODES) {
                as_[row] = ps;
                ad_[row] = pd;
            }
        }
    }
}

// ---------------- segment softmax + weighted aggregation (one wave per dst node)
// Gather: 16 lanes x 16B per edge; 16 edges per outer iteration (4 loads in
// flight per lane) to cover L2/L3 miss latency.
__global__ void k_aggregate(const int* __restrict__ row_ptr, const int* __restrict__ col_src,
                            const unsigned short* __restrict__ Hb,
                            const float* __restrict__ as_, const float* __restrict__ ad_,
                            const float* __restrict__ bias, float* __restrict__ Zout,
                            float* __restrict__ ebuf) {
    int node = blockIdx.x * 4 + (threadIdx.x >> 6);
    int lane = threadIdx.x & 63;
    if (node >= N_NODES) return;
    int g = lane >> 4;       // edge group 0..3
    int fl = lane & 15;      // feature lanes: features fl*8 .. fl*8+7

    int start = row_ptr[node], end = row_ptr[node + 1];
    int deg = end - start;
    float ad_i = ad_[node];
    float eself = lrelu(as_[node] + ad_i);
    float m = eself;
    float acc[8];
#pragma unroll
    for (int f = 0; f < 8; ++f) acc[f] = 0.f;
    float wself;

    if (deg <= 128) {
        int s0 = 0, s1 = 0;
        float e0 = -INFINITY, e1 = -INFINITY;
        if (start + lane < end) {
            s0 = col_src[start + lane];
            e0 = lrelu(as_[s0] + ad_i);
            m = fmaxf(m, e0);
        }
        if (start + 64 + lane < end) {
            s1 = col_src[start + 64 + lane];
            e1 = lrelu(as_[s1] + ad_i);
            m = fmaxf(m, e1);
        }
#pragma unroll
        for (int off = 32; off; off >>= 1) m = fmaxf(m, __shfl_xor(m, off));
        float w0 = __expf(e0 - m);   // 0 for invalid lanes
        float w1 = __expf(e1 - m);
        float p = w0 + w1;
#pragma unroll
        for (int off = 32; off; off >>= 1) p += __shfl_xor(p, off);
        float pself = __expf(eself - m);
        float inv_s = 1.f / (p + pself);
        w0 *= inv_s;
        w1 *= inv_s;
        wself = pself * inv_s;

        int jmax = deg < 64 ? deg : 64;
        int j = 0;
        // 16 edges per iteration: 4 independent dwordx4 loads in flight/lane
        for (; j + 16 <= jmax; j += 16) {
            float w[4]; int sv[4];
#pragma unroll
            for (int u = 0; u < 4; ++u) {
                int idx = j + u * 4 + g;
                w[u] = __shfl(w0, idx);
                sv[u] = __shfl(s0, idx);
            }
            uint4 hv[4];
#pragma unroll
            for (int u = 0; u < 4; ++u)
                hv[u] = *(const uint4*)&Hb[(size_t)sv[u] * 128 + fl * 8];
#pragma unroll
            for (int u = 0; u < 4; ++u) {
                float2 a0 = bf2f2(hv[u].x), a1 = bf2f2(hv[u].y);
                float2 a2 = bf2f2(hv[u].z), a3 = bf2f2(hv[u].w);
                acc[0] += w[u] * a0.x; acc[1] += w[u] * a0.y;
                acc[2] += w[u] * a1.x; acc[3] += w[u] * a1.y;
                acc[4] += w[u] * a2.x; acc[5] += w[u] * a2.y;
                acc[6] += w[u] * a3.x; acc[7] += w[u] * a3.y;
            }
        }
        for (; j < jmax; j += 4) {
            int idx = j + g;                       // <= 63 always; w0=0 past deg
            float w = __shfl(w0, idx);
            int sv = __shfl(s0, idx);
            uint4 hv = *(const uint4*)&Hb[(size_t)sv * 128 + fl * 8];
            float2 a0 = bf2f2(hv.x), a1 = bf2f2(hv.y), a2 = bf2f2(hv.z), a3 = bf2f2(hv.w);
            acc[0] += w * a0.x; acc[1] += w * a0.y;
            acc[2] += w * a1.x; acc[3] += w * a1.y;
            acc[4] += w * a2.x; acc[5] += w * a2.y;
            acc[6] += w * a3.x; acc[7] += w * a3.y;
        }
        for (int j2 = 64; j2 < deg; j2 += 4) {     // rare (deg>64)
            int idx = j2 - 64 + g;
            float w = __shfl(w1, idx);
            int sv = __shfl(s1, idx);
            uint4 hv = *(const uint4*)&Hb[(size_t)sv * 128 + fl * 8];
            float2 a0 = bf2f2(hv.x), a1 = bf2f2(hv.y), a2 = bf2f2(hv.z), a3 = bf2f2(hv.w);
            acc[0] += w * a0.x; acc[1] += w * a0.y;
            acc[2] += w * a1.x; acc[3] += w * a1.y;
            acc[4] += w * a2.x; acc[5] += w * a2.y;
            acc[6] += w * a3.x; acc[7] += w * a3.y;
        }
    } else {
        for (int j = start + lane; j < end; j += 64) {
            int sj = col_src[j];
            float e = lrelu(as_[sj] + ad_i);
            ebuf[j] = e;
            m = fmaxf(m, e);
        }
#pragma unroll
        for (int off = 32; off; off >>= 1) m = fmaxf(m, __shfl_xor(m, off));
        float p = 0.f;
        for (int j = start + lane; j < end; j += 64) p += __expf(ebuf[j] - m);
#pragma unroll
        for (int off = 32; off; off >>= 1) p += __shfl_xor(p, off);
        float pself = __expf(eself - m);
        float inv_s = 1.f / (p + pself);
        wself = pself * inv_s;
        for (int j = start; j < end; j += 4) {
            int e = j + g;
            float w = 0.f;
            int sv = 0;
            if (e < end) {
                w = __expf(ebuf[e] - m) * inv_s;
                sv = col_src[e];
            }
            uint4 hv = *(const uint4*)&Hb[(size_t)sv * 128 + fl * 8];
            float2 a0 = bf2f2(hv.x), a1 = bf2f2(hv.y), a2 = bf2f2(hv.z), a3 = bf2f2(hv.w);
            acc[0] += w * a0.x; acc[1] += w * a0.y;
            acc[2] += w * a1.x; acc[3] += w * a1.y;
            acc[4] += w * a2.x; acc[5] += w * a2.y;
            acc[6] += w * a3.x; acc[7] += w * a3.y;
        }
    }

    // combine the 4 edge-group partials
#pragma unroll
    for (int f = 0; f < 8; ++f) {
        acc[f] += __shfl_xor(acc[f], 16);
        acc[f] += __shfl_xor(acc[f], 32);
    }

    if (g == 0) {
        uint4 hv = *(const uint4*)&Hb[(size_t)node * 128 + fl * 8];
        float2 a0 = bf2f2(hv.x), a1 = bf2f2(hv.y), a2 = bf2f2(hv.z), a3 = bf2f2(hv.w);
        float4 b0 = *(const float4*)&bias[fl * 8];
        float4 b1 = *(const float4*)&bias[fl * 8 + 4];
        float4 o0, o1;
        o0.x = acc[0] + wself * a0.x + b0.x;
        o0.y = acc[1] + wself * a0.y + b0.y;
        o0.z = acc[2] + wself * a1.x + b0.z;
        o0.w = acc[3] + wself * a1.y + b0.w;
        o1.x = acc[4] + wself * a2.x + b1.x;
        o1.y = acc[5] + wself * a2.y + b1.y;
        o1.z = acc[6] + wself * a3.x + b1.z;
        o1.w = acc[7] + wself * a3.y + b1.w;
        *(float4*)&Zout[(size_t)node * 128 + fl * 8] = o0;
        *(float4*)&Zout[(size_t)node * 128 + fl * 8 + 4] = o1;
    }
}

// ---------------- BatchNorm stats (training, biased var)
__global__ void k_bnstats(const float* __restrict__ Z, float* __restrict__ part) {
    int c = threadIdx.x;
    float s = 0.f, sq = 0.f;
    for (int i = blockIdx.x; i < N_NODES; i += gridDim.x) {
        float v = Z[(size_t)i * 128 + c];
        s += v;
        sq += v * v;
    }
    part[blockIdx.x * 256 + c] = s;
    part[blockIdx.x * 256 + 128 + c] = sq;
}

__global__ void k_bnfinal(const float* __restrict__ part, float* __restrict__ mu,
                          float* __restrict__ rs) {
    __shared__ float ss[4][128];
    __shared__ float sqq[4][128];
    int c = threadIdx.x & 127;
    int q = threadIdx.x >> 7;   // 0..3
    float s = 0.f, sq = 0.f;
    for (int b = q; b < 512; b += 4) {
        s += part[b * 256 + c];
        sq += part[b * 256 + 128 + c];
    }
    ss[q][c] = s;
    sqq[q][c] = sq;
    __syncthreads();
    if (q == 0) {
        s = ss[0][c] + ss[1][c] + ss[2][c] + ss[3][c];
        sq = sqq[0][c] + sqq[1][c] + sqq[2][c] + sqq[3][c];
        float m = s / (float)N_NODES;
        float var = sq / (float)N_NODES - m * m;
        mu[c] = m;
        rs[c] = rsqrtf(var + EPS);
    }
}

// final-layer BN+ReLU apply -> fp32 out
__global__ void k_bnapply(const float* __restrict__ Zin, const float* __restrict__ mu,
                          const float* __restrict__ rs, float* __restrict__ Zout) {
    int idx = blockIdx.x * blockDim.x + threadIdx.x;
    if (idx >= N_NODES * 32) return;
    int c4 = idx & 31;
    float4 v = ((const float4*)Zin)[idx];
    float4 m4 = ((const float4*)mu)[c4];
    float4 r4 = ((const float4*)rs)[c4];
    v.x = fmaxf((v.x - m4.x) * r4.x, 0.f);
    v.y = fmaxf((v.y - m4.y) * r4.y, 0.f);
    v.z = fmaxf((v.z - m4.z) * r4.z, 0.f);
    v.w = fmaxf((v.w - m4.w) * r4.w, 0.f);
    ((float4*)Zout)[idx] = v;
}

extern "C" void kernel_launch(void* const* d_in, const int* in_sizes, int n_in,
                              void* d_out, int out_size, void* d_ws, size_t ws_size,
                              hipStream_t stream) {
    const float* x = (const float*)d_in[0];
    const int* ei = (const int*)d_in[1];
    const int* srcp = ei;
    const int* dstp = ei + N_EDGES;
    const float* W = (const float*)d_in[2];
    const float* a_src = (const float*)d_in[3];
    const float* a_dst = (const float*)d_in[4];
    const float* bias = (const float*)d_in[5];
    float* out = (float*)d_out;

    char* ws = (char*)d_ws;
    size_t off = 0;
    auto alloc = [&](size_t bytes) -> void* {
        void* p = ws + off;
        off = (off + bytes + 255) & ~(size_t)255;
        return p;
    };
    int* bcnt     = (int*)alloc(NBUCK * 4);
    int* bbase    = (int*)alloc((NBUCK + 1) * 4);
    int* gtail    = (int*)alloc(NBUCK * 4);
    int* row_ptr  = (int*)alloc((N_NODES + 1) * 4);
    int* col_src  = (int*)alloc(N_EDGES * 4);
    uint2* staged = (uint2*)alloc((size_t)N_EDGES * 8);   // aliased by ebuf later
    unsigned short* hbf = (unsigned short*)alloc((size_t)N_NODES * DIM * 2);
    float* zbuf   = (float*)alloc((size_t)N_NODES * DIM * 4);
    unsigned short* wtb = (unsigned short*)alloc(3 * 16384 * 2);
    float* asb    = (float*)alloc(N_NODES * 4);
    float* adb    = (float*)alloc(N_NODES * 4);
    float* part   = (float*)alloc(512 * 256 * 4);
    float* mu     = (float*)alloc(128 * 4);
    float* rsg    = (float*)alloc(128 * 4);
    if (off > ws_size) return;

    float* ebuf = (float*)staged;   // aggregate-only scratch (after partC done)

    hipMemsetAsync(bcnt, 0, NBUCK * 4, stream);
    k_hist<<<256, 256, 0, stream>>>(dstp, bcnt);
    k_bscan<<<1, NBUCK, 0, stream>>>(bcnt, bbase, gtail);
    k_partB<<<NBLK_B, 256, 0, stream>>>(srcp, dstp, gtail, staged);
    k_partC<<<NBUCK, 256, 0, stream>>>(staged, bbase, row_ptr, col_src);
    k_prepW<<<192, 256, 0, stream>>>(W, wtb);

    const float* zin = x;
    for (int l = 0; l < 3; ++l) {
        k_gemm_mfma<<<(N_NODES + 127) / 128, 256, 0, stream>>>(
            zin, wtb + l * 16384, hbf, (l == 0) ? nullptr : mu, rsg,
            a_src + l * DIM, a_dst + l * DIM, asb, adb);
        k_aggregate<<<(N_NODES + 3) / 4, 256, 0, stream>>>(row_ptr, col_src, hbf, asb, adb,
                                                           bias + l * DIM, zbuf, ebuf);
        k_bnstats<<<512, 128, 0, stream>>>(zbuf, part);
        k_bnfinal<<<1, 512, 0, stream>>>(part, mu, rsg);
        if (l == 2)
            k_bnapply<<<(N_NODES * 32 + 255) / 256, 256, 0, stream>>>(zbuf, mu, rsg, out);
        zin = zbuf;
    }
}